// Round 1
// baseline (1387.190 us; speedup 1.0000x reference)
//
#include <hip/hip_runtime.h>
#include <hip/hip_bf16.h>
#include <math.h>

#define NN 100000      // nodes
#define NE 1600000     // edges
#define HD 64          // feature dim
#define NG 1000        // graphs
#define NC 10          // classes

// ---------------- degree ----------------
__global__ void deg_init(float* __restrict__ deg) {
    int i = blockIdx.x * blockDim.x + threadIdx.x;
    if (i < NN) deg[i] = 1.0f;   // self-loop
}

__global__ void deg_acc(const int* __restrict__ dst, float* __restrict__ deg) {
    int e = blockIdx.x * blockDim.x + threadIdx.x;
    if (e < NE) atomicAdd(&deg[dst[e]], 1.0f);
}

__global__ void deg_rsqrt(float* __restrict__ deg) {
    int i = blockIdx.x * blockDim.x + threadIdx.x;
    if (i < NN) deg[i] = rsqrtf(deg[i]);
}

// ---------------- per-layer GEMM: y = (h @ W^T) * dinv ; hout = y * dinv (self-loop init) ----------------
// W is [64][64] row-major; lane l holds W[l][k] k=0..63 in registers.
__global__ __launch_bounds__(256) void gemm_scale(const float* __restrict__ h,
                                                  const float* __restrict__ W,
                                                  const float* __restrict__ dinv,
                                                  float* __restrict__ y,
                                                  float* __restrict__ hout,
                                                  int nrows)
{
    const int lane = threadIdx.x & 63;
    const int wave = threadIdx.x >> 6;

    float Wreg[64];
    const float4* Wv = (const float4*)(W + lane * 64);
#pragma unroll
    for (int k4 = 0; k4 < 16; ++k4) {
        float4 wv = Wv[k4];
        Wreg[k4 * 4 + 0] = wv.x; Wreg[k4 * 4 + 1] = wv.y;
        Wreg[k4 * 4 + 2] = wv.z; Wreg[k4 * 4 + 3] = wv.w;
    }

#pragma unroll 1
    for (int i = 0; i < 16; ++i) {
        int r = blockIdx.x * 64 + i * 4 + wave;
        if (r >= nrows) break;
        const float4* hrow = (const float4*)(h + r * 64);
        float a0 = 0.f, a1 = 0.f, a2 = 0.f, a3 = 0.f;
#pragma unroll
        for (int k4 = 0; k4 < 16; ++k4) {
            float4 hv = hrow[k4];            // wave-uniform broadcast load
            a0 = fmaf(hv.x, Wreg[k4 * 4 + 0], a0);
            a1 = fmaf(hv.y, Wreg[k4 * 4 + 1], a1);
            a2 = fmaf(hv.z, Wreg[k4 * 4 + 2], a2);
            a3 = fmaf(hv.w, Wreg[k4 * 4 + 3], a3);
        }
        float acc = (a0 + a1) + (a2 + a3);
        float di = dinv[r];
        float yv = acc * di;
        y[r * 64 + lane]    = yv;        // scaled by dinv[src] for the gather
        hout[r * 64 + lane] = yv * di;   // self-loop term xw*dinv^2
    }
}

// ---------------- edge aggregation: hout[dst] += y[src] * dinv[dst] ----------------
#define EPW 4   // edges per wave
__global__ __launch_bounds__(256) void edge_aggr(const int* __restrict__ src,
                                                 const int* __restrict__ dst,
                                                 const float* __restrict__ y,
                                                 const float* __restrict__ dinv,
                                                 float* __restrict__ hout)
{
    int wave = (blockIdx.x * blockDim.x + threadIdx.x) >> 6;
    int lane = threadIdx.x & 63;
    int e0 = wave * EPW;
#pragma unroll
    for (int j = 0; j < EPW; ++j) {
        int e = e0 + j;
        if (e >= NE) return;
        int s = src[e];                  // wave-uniform broadcast
        int d = dst[e];
        float w = dinv[d];
        float v = y[s * 64 + lane] * w;  // coalesced 256B gather
        atomicAdd(&hout[d * 64 + lane], v);
    }
}

// ---------------- bias + relu in place ----------------
__global__ void bias_relu(float* __restrict__ h, const float* __restrict__ b, int n64) {
    int i = blockIdx.x * blockDim.x + threadIdx.x;
    if (i < n64) {
        float v = h[i] + b[i & 63];
        h[i] = v > 0.f ? v : 0.f;
    }
}

// ---------------- pool (mean per graph, batch sorted) + FFN + softmax ----------------
__global__ __launch_bounds__(64) void pool_ffn(const float* __restrict__ h3,
                                               const int* __restrict__ batch,
                                               const float* __restrict__ Wf,
                                               const float* __restrict__ bf,
                                               float* __restrict__ pooled,
                                               float* __restrict__ ffn,
                                               float* __restrict__ soft)
{
    int g = blockIdx.x;
    int lane = threadIdx.x;

    // lower_bound for g and g+1 on sorted batch
    int lo = 0, hi = NN;
    while (lo < hi) { int mid = (lo + hi) >> 1; if (batch[mid] < g) lo = mid + 1; else hi = mid; }
    int start = lo;
    lo = start; hi = NN;
    while (lo < hi) { int mid = (lo + hi) >> 1; if (batch[mid] < g + 1) lo = mid + 1; else hi = mid; }
    int end = lo;

    float acc = 0.f;
    for (int n = start; n < end; ++n) acc += h3[n * 64 + lane];
    float cnt = (float)(end - start);
    float pv = acc / fmaxf(cnt, 1.0f);
    pooled[g * 64 + lane] = pv;

    // ffn: f[cls] = relu(sum_k pv[k]*Wf[cls][k] + bf[cls])
    float f = 0.f;
#pragma unroll
    for (int cls = 0; cls < NC; ++cls) {
        float v = pv * Wf[cls * 64 + lane];
#pragma unroll
        for (int off = 32; off; off >>= 1) v += __shfl_xor(v, off);
        if (lane == cls) f = v;
    }
    float fb = (lane < NC) ? fmaxf(f + bf[lane], 0.f) : -INFINITY;
    if (lane < NC) ffn[g * NC + lane] = fb;

    // softmax over lanes 0..9
    float m = fb;
#pragma unroll
    for (int off = 32; off; off >>= 1) m = fmaxf(m, __shfl_xor(m, off));
    float e = (lane < NC) ? expf(fb - m) : 0.f;
    float s = e;
#pragma unroll
    for (int off = 32; off; off >>= 1) s += __shfl_xor(s, off);
    if (lane < NC) soft[g * NC + lane] = e / s;
}

extern "C" void kernel_launch(void* const* d_in, const int* in_sizes, int n_in,
                              void* d_out, int out_size, void* d_ws, size_t ws_size,
                              hipStream_t stream) {
    const float* x   = (const float*)d_in[0];
    const int*   ei  = (const int*)d_in[1];
    const int*   bat = (const int*)d_in[2];
    const float* W1  = (const float*)d_in[3];
    const float* b1  = (const float*)d_in[4];
    const float* W2  = (const float*)d_in[5];
    const float* b2  = (const float*)d_in[6];
    const float* W3  = (const float*)d_in[7];
    const float* b3  = (const float*)d_in[8];
    const float* Wf  = (const float*)d_in[9];
    const float* bf  = (const float*)d_in[10];

    const int* src = ei;
    const int* dst = ei + NE;

    float* out    = (float*)d_out;
    float* h1     = out;
    float* h2     = out + (size_t)NN * HD;
    float* h3     = out + (size_t)2 * NN * HD;
    float* pooled = out + (size_t)3 * NN * HD;
    float* ffn    = pooled + (size_t)NG * HD;
    float* soft   = ffn + (size_t)NG * NC;

    float* dinv = (float*)d_ws;              // NN floats
    float* y    = dinv + NN;                 // NN*HD floats (offset 400000B, 16B-aligned)

    // degree -> dinv
    deg_init<<<(NN + 255) / 256, 256, 0, stream>>>(dinv);
    deg_acc<<<(NE + 255) / 256, 256, 0, stream>>>(dst, dinv);
    deg_rsqrt<<<(NN + 255) / 256, 256, 0, stream>>>(dinv);

    const int gemmGrid = (NN + 63) / 64;
    const int edgeGrid = NE / (EPW * 4);     // 4 waves/block, EPW edges/wave
    const int brGrid   = (NN * HD + 255) / 256;

    // layer 1: x -> h1
    gemm_scale<<<gemmGrid, 256, 0, stream>>>(x, W1, dinv, y, h1, NN);
    edge_aggr<<<edgeGrid, 256, 0, stream>>>(src, dst, y, dinv, h1);
    bias_relu<<<brGrid, 256, 0, stream>>>(h1, b1, NN * HD);

    // layer 2: h1 -> h2
    gemm_scale<<<gemmGrid, 256, 0, stream>>>(h1, W2, dinv, y, h2, NN);
    edge_aggr<<<edgeGrid, 256, 0, stream>>>(src, dst, y, dinv, h2);
    bias_relu<<<brGrid, 256, 0, stream>>>(h2, b2, NN * HD);

    // layer 3: h2 -> h3
    gemm_scale<<<gemmGrid, 256, 0, stream>>>(h2, W3, dinv, y, h3, NN);
    edge_aggr<<<edgeGrid, 256, 0, stream>>>(src, dst, y, dinv, h3);
    bias_relu<<<brGrid, 256, 0, stream>>>(h3, b3, NN * HD);

    // pool + ffn + softmax
    pool_ffn<<<NG, 64, 0, stream>>>(h3, bat, Wf, bf, pooled, ffn, soft);
}

// Round 2
// 847.790 us; speedup vs baseline: 1.6362x; 1.6362x over previous
//
#include <hip/hip_runtime.h>
#include <hip/hip_bf16.h>
#include <math.h>

#define NN 100000      // nodes
#define NE 1600000     // edges
#define HD 64          // feature dim
#define NG 1000        // graphs
#define NC 10          // classes

// ---------------- CSR build: histogram ----------------
__global__ void hist_dst(const int* __restrict__ dst, int* __restrict__ cnt) {
    int e = blockIdx.x * blockDim.x + threadIdx.x;
    if (e < NE) atomicAdd(&cnt[dst[e]], 1);
}

// ---------------- one-block scan: cnt -> rowstart (exclusive), dinv = rsqrt(cnt+1) ----------------
#define SCAN_T 1024
__global__ __launch_bounds__(SCAN_T) void scan_csr(const int* __restrict__ cnt,
                                                   int* __restrict__ rowstart,
                                                   float* __restrict__ dinv)
{
    __shared__ int part[SCAN_T];
    int t = threadIdx.x;
    const int CH = (NN + SCAN_T - 1) / SCAN_T;   // 98
    int lo = t * CH;
    int hi = lo + CH; if (hi > NN) hi = NN;
    int s = 0;
    for (int i = lo; i < hi; ++i) s += cnt[i];
    part[t] = s;
    __syncthreads();
    // Hillis-Steele inclusive scan
    for (int off = 1; off < SCAN_T; off <<= 1) {
        int v = (t >= off) ? part[t - off] : 0;
        __syncthreads();
        part[t] += v;
        __syncthreads();
    }
    int run = (t > 0) ? part[t - 1] : 0;         // exclusive prefix of this chunk
    for (int i = lo; i < hi; ++i) {
        int c = cnt[i];
        rowstart[i] = run;
        dinv[i] = rsqrtf((float)c + 1.0f);
        run += c;
    }
    if (t == SCAN_T - 1) rowstart[NN] = run;     // == NE
}

// ---------------- CSR scatter: srcidx grouped by dst ----------------
__global__ void scatter_csr(const int* __restrict__ src, const int* __restrict__ dst,
                            const int* __restrict__ rowstart, int* __restrict__ cursor,
                            int* __restrict__ srcidx) {
    int e = blockIdx.x * blockDim.x + threadIdx.x;
    if (e < NE) {
        int d = dst[e];
        int p = atomicAdd(&cursor[d], 1);
        srcidx[rowstart[d] + p] = src[e];
    }
}

// ---------------- per-layer GEMM: y = (h @ W^T) * dinv ----------------
// W is [64][64] row-major; lane l holds W[l][k] k=0..63 in registers.
__global__ __launch_bounds__(256) void gemm_scale(const float* __restrict__ h,
                                                  const float* __restrict__ W,
                                                  const float* __restrict__ dinv,
                                                  float* __restrict__ y,
                                                  int nrows)
{
    const int lane = threadIdx.x & 63;
    const int wave = threadIdx.x >> 6;

    float Wreg[64];
    const float4* Wv = (const float4*)(W + lane * 64);
#pragma unroll
    for (int k4 = 0; k4 < 16; ++k4) {
        float4 wv = Wv[k4];
        Wreg[k4 * 4 + 0] = wv.x; Wreg[k4 * 4 + 1] = wv.y;
        Wreg[k4 * 4 + 2] = wv.z; Wreg[k4 * 4 + 3] = wv.w;
    }

#pragma unroll 1
    for (int i = 0; i < 16; ++i) {
        int r = blockIdx.x * 64 + i * 4 + wave;
        if (r >= nrows) break;
        const float4* hrow = (const float4*)(h + r * 64);
        float a0 = 0.f, a1 = 0.f, a2 = 0.f, a3 = 0.f;
#pragma unroll
        for (int k4 = 0; k4 < 16; ++k4) {
            float4 hv = hrow[k4];            // wave-uniform broadcast load
            a0 = fmaf(hv.x, Wreg[k4 * 4 + 0], a0);
            a1 = fmaf(hv.y, Wreg[k4 * 4 + 1], a1);
            a2 = fmaf(hv.z, Wreg[k4 * 4 + 2], a2);
            a3 = fmaf(hv.w, Wreg[k4 * 4 + 3], a3);
        }
        float acc = (a0 + a1) + (a2 + a3);
        y[(size_t)r * 64 + lane] = acc * dinv[r];   // pre-scaled by dinv[src]
    }
}

// ---------------- pull aggregation: h[n] = relu((y[n] + sum_in y[src]) * dinv[n] + b) ----------------
__global__ __launch_bounds__(256) void pull_aggr(const int* __restrict__ rowstart,
                                                 const int* __restrict__ srcidx,
                                                 const float* __restrict__ y,
                                                 const float* __restrict__ dinv,
                                                 const float* __restrict__ bias,
                                                 float* __restrict__ hout)
{
    int wid = (blockIdx.x * blockDim.x + threadIdx.x) >> 6;
    int lane = threadIdx.x & 63;
    if (wid >= NN) return;
    int s0 = rowstart[wid], s1 = rowstart[wid + 1];
    float acc = y[(size_t)wid * 64 + lane];          // self-loop term (y = xw*dinv)
    for (int base = s0; base < s1; base += 64) {
        int nb = s1 - base; if (nb > 64) nb = 64;
        int idx = (lane < nb) ? srcidx[base + lane] : 0;   // coalesced batch of indices
        int j = 0;
        for (; j + 4 <= nb; j += 4) {                 // 4 independent gathers in flight
            int i0 = __shfl(idx, j + 0), i1 = __shfl(idx, j + 1);
            int i2 = __shfl(idx, j + 2), i3 = __shfl(idx, j + 3);
            float v0 = y[(size_t)i0 * 64 + lane];
            float v1 = y[(size_t)i1 * 64 + lane];
            float v2 = y[(size_t)i2 * 64 + lane];
            float v3 = y[(size_t)i3 * 64 + lane];
            acc += v0; acc += v1; acc += v2; acc += v3;
        }
        for (; j < nb; ++j) {
            int s = __shfl(idx, j);
            acc += y[(size_t)s * 64 + lane];
        }
    }
    float v = fmaf(acc, dinv[wid], bias[lane]);
    hout[(size_t)wid * 64 + lane] = fmaxf(v, 0.f);
}

// ---------------- pool (mean per graph, batch sorted) + FFN + softmax ----------------
__global__ __launch_bounds__(64) void pool_ffn(const float* __restrict__ h3,
                                               const int* __restrict__ batch,
                                               const float* __restrict__ Wf,
                                               const float* __restrict__ bf,
                                               float* __restrict__ pooled,
                                               float* __restrict__ ffn,
                                               float* __restrict__ soft)
{
    int g = blockIdx.x;
    int lane = threadIdx.x;

    int lo = 0, hi = NN;
    while (lo < hi) { int mid = (lo + hi) >> 1; if (batch[mid] < g) lo = mid + 1; else hi = mid; }
    int start = lo;
    lo = start; hi = NN;
    while (lo < hi) { int mid = (lo + hi) >> 1; if (batch[mid] < g + 1) lo = mid + 1; else hi = mid; }
    int end = lo;

    float acc = 0.f;
    for (int n = start; n < end; ++n) acc += h3[(size_t)n * 64 + lane];
    float cnt = (float)(end - start);
    float pv = acc / fmaxf(cnt, 1.0f);
    pooled[g * 64 + lane] = pv;

    float f = 0.f;
#pragma unroll
    for (int cls = 0; cls < NC; ++cls) {
        float v = pv * Wf[cls * 64 + lane];
#pragma unroll
        for (int off = 32; off; off >>= 1) v += __shfl_xor(v, off);
        if (lane == cls) f = v;
    }
    float fb = (lane < NC) ? fmaxf(f + bf[lane], 0.f) : -INFINITY;
    if (lane < NC) ffn[g * NC + lane] = fb;

    float m = fb;
#pragma unroll
    for (int off = 32; off; off >>= 1) m = fmaxf(m, __shfl_xor(m, off));
    float e = (lane < NC) ? expf(fb - m) : 0.f;
    float s = e;
#pragma unroll
    for (int off = 32; off; off >>= 1) s += __shfl_xor(s, off);
    if (lane < NC) soft[g * NC + lane] = e / s;
}

extern "C" void kernel_launch(void* const* d_in, const int* in_sizes, int n_in,
                              void* d_out, int out_size, void* d_ws, size_t ws_size,
                              hipStream_t stream) {
    const float* x   = (const float*)d_in[0];
    const int*   ei  = (const int*)d_in[1];
    const int*   bat = (const int*)d_in[2];
    const float* W1  = (const float*)d_in[3];
    const float* b1  = (const float*)d_in[4];
    const float* W2  = (const float*)d_in[5];
    const float* b2  = (const float*)d_in[6];
    const float* W3  = (const float*)d_in[7];
    const float* b3  = (const float*)d_in[8];
    const float* Wf  = (const float*)d_in[9];
    const float* bf  = (const float*)d_in[10];

    const int* src = ei;
    const int* dst = ei + NE;

    float* out    = (float*)d_out;
    float* h1     = out;
    float* h2     = out + (size_t)NN * HD;
    float* h3     = out + (size_t)2 * NN * HD;
    float* pooled = out + (size_t)3 * NN * HD;
    float* ffn    = pooled + (size_t)NG * HD;
    float* soft   = ffn + (size_t)NG * NC;

    // workspace layout (bytes):
    //   dinv     [NN f32]        @ 0
    //   y        [NN*64 f32]     @ 400000
    //   rowstart [NN+4 i32]      @ 26000000
    //   cnt      [NN i32]        @ 26400016   (also reused as scatter cursor)
    //   srcidx   [NE i32]        @ 26800016
    char* ws = (char*)d_ws;
    float* dinv     = (float*)(ws + 0);
    float* y        = (float*)(ws + 400000);
    int*   rowstart = (int*)  (ws + 26000000);
    int*   cnt      = (int*)  (ws + 26400016);
    int*   srcidx   = (int*)  (ws + 26800016);

    const int eGrid = (NE + 255) / 256;

    // ---- CSR build (amortized across all 3 layers) ----
    hipMemsetAsync(cnt, 0, NN * sizeof(int), stream);
    hist_dst<<<eGrid, 256, 0, stream>>>(dst, cnt);
    scan_csr<<<1, SCAN_T, 0, stream>>>(cnt, rowstart, dinv);
    hipMemsetAsync(cnt, 0, NN * sizeof(int), stream);
    scatter_csr<<<eGrid, 256, 0, stream>>>(src, dst, rowstart, cnt, srcidx);

    const int gemmGrid = (NN + 63) / 64;
    const int aggrGrid = (NN + 3) / 4;      // 4 waves (nodes) per 256-block

    gemm_scale<<<gemmGrid, 256, 0, stream>>>(x, W1, dinv, y, NN);
    pull_aggr<<<aggrGrid, 256, 0, stream>>>(rowstart, srcidx, y, dinv, b1, h1);

    gemm_scale<<<gemmGrid, 256, 0, stream>>>(h1, W2, dinv, y, NN);
    pull_aggr<<<aggrGrid, 256, 0, stream>>>(rowstart, srcidx, y, dinv, b2, h2);

    gemm_scale<<<gemmGrid, 256, 0, stream>>>(h2, W3, dinv, y, NN);
    pull_aggr<<<aggrGrid, 256, 0, stream>>>(rowstart, srcidx, y, dinv, b3, h3);

    pool_ffn<<<NG, 64, 0, stream>>>(h3, bat, Wf, bf, pooled, ffn, soft);
}

// Round 3
// 633.362 us; speedup vs baseline: 2.1902x; 1.3386x over previous
//
#include <hip/hip_runtime.h>
#include <hip/hip_bf16.h>
#include <math.h>

#define NN 100000      // nodes
#define NE 1600000     // edges
#define HD 64          // feature dim
#define NG 1000        // graphs
#define NC 10          // classes

#define SCAN_B 256
#define SCAN_NB ((NN + SCAN_B - 1) / SCAN_B)   // 391

// ---------------- CSR build: histogram ----------------
__global__ void hist_dst(const int* __restrict__ dst, int* __restrict__ cnt) {
    int e = blockIdx.x * blockDim.x + threadIdx.x;
    if (e < NE) atomicAdd(&cnt[dst[e]], 1);
}

// ---------------- scan phase A: per-block sums ----------------
__global__ __launch_bounds__(SCAN_B) void scan_partial(const int* __restrict__ cnt,
                                                       int* __restrict__ blocksum)
{
    __shared__ int sm[SCAN_B];
    int t = threadIdx.x;
    int i = blockIdx.x * SCAN_B + t;
    sm[t] = (i < NN) ? cnt[i] : 0;
    __syncthreads();
    for (int off = SCAN_B / 2; off > 0; off >>= 1) {
        if (t < off) sm[t] += sm[t + off];
        __syncthreads();
    }
    if (t == 0) blocksum[blockIdx.x] = sm[0];
}

// ---------------- scan phase B: scan the 391 block sums (one block) ----------------
__global__ __launch_bounds__(512) void scan_blocksums(int* __restrict__ blocksum,
                                                      int* __restrict__ blockoff)
{
    __shared__ int sm[512];
    int t = threadIdx.x;
    int v = (t < SCAN_NB) ? blocksum[t] : 0;
    sm[t] = v;
    __syncthreads();
    for (int off = 1; off < 512; off <<= 1) {
        int u = (t >= off) ? sm[t - off] : 0;
        __syncthreads();
        sm[t] += u;
        __syncthreads();
    }
    if (t < SCAN_NB) blockoff[t] = sm[t] - v;   // exclusive
}

// ---------------- scan phase C: local scan + offset -> rowstart, dinv ----------------
__global__ __launch_bounds__(SCAN_B) void scan_final(const int* __restrict__ cnt,
                                                     const int* __restrict__ blockoff,
                                                     int* __restrict__ rowstart,
                                                     float* __restrict__ dinv)
{
    __shared__ int sm[SCAN_B];
    int t = threadIdx.x;
    int i = blockIdx.x * SCAN_B + t;
    int v = (i < NN) ? cnt[i] : 0;
    sm[t] = v;
    __syncthreads();
    for (int off = 1; off < SCAN_B; off <<= 1) {
        int u = (t >= off) ? sm[t - off] : 0;
        __syncthreads();
        sm[t] += u;
        __syncthreads();
    }
    if (i < NN) {
        int incl = sm[t] + blockoff[blockIdx.x];
        rowstart[i] = incl - v;                 // exclusive
        dinv[i] = rsqrtf((float)v + 1.0f);
        if (i == NN - 1) rowstart[NN] = incl;   // == NE
    }
}

// ---------------- CSR scatter: srcidx grouped by dst ----------------
__global__ void scatter_csr(const int* __restrict__ src, const int* __restrict__ dst,
                            const int* __restrict__ rowstart, int* __restrict__ cursor,
                            int* __restrict__ srcidx) {
    int e = blockIdx.x * blockDim.x + threadIdx.x;
    if (e < NE) {
        int d = dst[e];
        int p = atomicAdd(&cursor[d], 1);
        srcidx[rowstart[d] + p] = src[e];
    }
}

// ---------------- per-layer GEMM: y = (h @ W^T) * dinv ----------------
__global__ __launch_bounds__(256) void gemm_scale(const float* __restrict__ h,
                                                  const float* __restrict__ W,
                                                  const float* __restrict__ dinv,
                                                  float* __restrict__ y,
                                                  int nrows)
{
    const int lane = threadIdx.x & 63;
    const int wave = threadIdx.x >> 6;

    float Wreg[64];
    const float4* Wv = (const float4*)(W + lane * 64);
#pragma unroll
    for (int k4 = 0; k4 < 16; ++k4) {
        float4 wv = Wv[k4];
        Wreg[k4 * 4 + 0] = wv.x; Wreg[k4 * 4 + 1] = wv.y;
        Wreg[k4 * 4 + 2] = wv.z; Wreg[k4 * 4 + 3] = wv.w;
    }

#pragma unroll 1
    for (int i = 0; i < 16; ++i) {
        int r = blockIdx.x * 64 + i * 4 + wave;
        if (r >= nrows) break;
        const float4* hrow = (const float4*)(h + r * 64);
        float a0 = 0.f, a1 = 0.f, a2 = 0.f, a3 = 0.f;
#pragma unroll
        for (int k4 = 0; k4 < 16; ++k4) {
            float4 hv = hrow[k4];            // wave-uniform broadcast load
            a0 = fmaf(hv.x, Wreg[k4 * 4 + 0], a0);
            a1 = fmaf(hv.y, Wreg[k4 * 4 + 1], a1);
            a2 = fmaf(hv.z, Wreg[k4 * 4 + 2], a2);
            a3 = fmaf(hv.w, Wreg[k4 * 4 + 3], a3);
        }
        float acc = (a0 + a1) + (a2 + a3);
        y[(size_t)r * 64 + lane] = acc * dinv[r];   // pre-scaled by dinv[src]
    }
}

// ---------------- pull aggregation: h[n] = relu((y[n] + sum_in y[src]) * dinv[n] + b) ----------------
__global__ __launch_bounds__(256) void pull_aggr(const int* __restrict__ rowstart,
                                                 const int* __restrict__ srcidx,
                                                 const float* __restrict__ y,
                                                 const float* __restrict__ dinv,
                                                 const float* __restrict__ bias,
                                                 float* __restrict__ hout)
{
    int wid = (blockIdx.x * blockDim.x + threadIdx.x) >> 6;
    int lane = threadIdx.x & 63;
    if (wid >= NN) return;
    int s0 = rowstart[wid], s1 = rowstart[wid + 1];
    float acc = y[(size_t)wid * 64 + lane];          // self-loop term (y = xw*dinv)
    for (int base = s0; base < s1; base += 64) {
        int nb = s1 - base; if (nb > 64) nb = 64;
        int idx = (lane < nb) ? srcidx[base + lane] : 0;   // coalesced batch of indices
        int j = 0;
        for (; j + 4 <= nb; j += 4) {                 // 4 independent gathers in flight
            int i0 = __shfl(idx, j + 0), i1 = __shfl(idx, j + 1);
            int i2 = __shfl(idx, j + 2), i3 = __shfl(idx, j + 3);
            float v0 = y[(size_t)i0 * 64 + lane];
            float v1 = y[(size_t)i1 * 64 + lane];
            float v2 = y[(size_t)i2 * 64 + lane];
            float v3 = y[(size_t)i3 * 64 + lane];
            acc += v0; acc += v1; acc += v2; acc += v3;
        }
        for (; j < nb; ++j) {
            int s = __shfl(idx, j);
            acc += y[(size_t)s * 64 + lane];
        }
    }
    float v = fmaf(acc, dinv[wid], bias[lane]);
    hout[(size_t)wid * 64 + lane] = fmaxf(v, 0.f);
}

// ---------------- pool (mean per graph, batch sorted) + FFN + softmax ----------------
__global__ __launch_bounds__(64) void pool_ffn(const float* __restrict__ h3,
                                               const int* __restrict__ batch,
                                               const float* __restrict__ Wf,
                                               const float* __restrict__ bf,
                                               float* __restrict__ pooled,
                                               float* __restrict__ ffn,
                                               float* __restrict__ soft)
{
    int g = blockIdx.x;
    int lane = threadIdx.x;

    int lo = 0, hi = NN;
    while (lo < hi) { int mid = (lo + hi) >> 1; if (batch[mid] < g) lo = mid + 1; else hi = mid; }
    int start = lo;
    lo = start; hi = NN;
    while (lo < hi) { int mid = (lo + hi) >> 1; if (batch[mid] < g + 1) lo = mid + 1; else hi = mid; }
    int end = lo;

    float acc = 0.f;
    for (int n = start; n < end; ++n) acc += h3[(size_t)n * 64 + lane];
    float cnt = (float)(end - start);
    float pv = acc / fmaxf(cnt, 1.0f);
    pooled[g * 64 + lane] = pv;

    float f = 0.f;
#pragma unroll
    for (int cls = 0; cls < NC; ++cls) {
        float v = pv * Wf[cls * 64 + lane];
#pragma unroll
        for (int off = 32; off; off >>= 1) v += __shfl_xor(v, off);
        if (lane == cls) f = v;
    }
    float fb = (lane < NC) ? fmaxf(f + bf[lane], 0.f) : -INFINITY;
    if (lane < NC) ffn[g * NC + lane] = fb;

    float m = fb;
#pragma unroll
    for (int off = 32; off; off >>= 1) m = fmaxf(m, __shfl_xor(m, off));
    float e = (lane < NC) ? expf(fb - m) : 0.f;
    float s = e;
#pragma unroll
    for (int off = 32; off; off >>= 1) s += __shfl_xor(s, off);
    if (lane < NC) soft[g * NC + lane] = e / s;
}

extern "C" void kernel_launch(void* const* d_in, const int* in_sizes, int n_in,
                              void* d_out, int out_size, void* d_ws, size_t ws_size,
                              hipStream_t stream) {
    const float* x   = (const float*)d_in[0];
    const int*   ei  = (const int*)d_in[1];
    const int*   bat = (const int*)d_in[2];
    const float* W1  = (const float*)d_in[3];
    const float* b1  = (const float*)d_in[4];
    const float* W2  = (const float*)d_in[5];
    const float* b2  = (const float*)d_in[6];
    const float* W3  = (const float*)d_in[7];
    const float* b3  = (const float*)d_in[8];
    const float* Wf  = (const float*)d_in[9];
    const float* bf  = (const float*)d_in[10];

    const int* src = ei;
    const int* dst = ei + NE;

    float* out    = (float*)d_out;
    float* h1     = out;
    float* h2     = out + (size_t)NN * HD;
    float* h3     = out + (size_t)2 * NN * HD;
    float* pooled = out + (size_t)3 * NN * HD;
    float* ffn    = pooled + (size_t)NG * HD;
    float* soft   = ffn + (size_t)NG * NC;

    // workspace layout (bytes):
    //   dinv     [NN f32]        @ 0
    //   y        [NN*64 f32]     @ 400000
    //   rowstart [NN+4 i32]      @ 26000000
    //   cnt      [NN i32]        @ 26400016   (also reused as scatter cursor)
    //   srcidx   [NE i32]        @ 26800016
    //   blocksum [SCAN_NB i32]   @ 33200016
    //   blockoff [SCAN_NB i32]   @ 33202016
    char* ws = (char*)d_ws;
    float* dinv     = (float*)(ws + 0);
    float* y        = (float*)(ws + 400000);
    int*   rowstart = (int*)  (ws + 26000000);
    int*   cnt      = (int*)  (ws + 26400016);
    int*   srcidx   = (int*)  (ws + 26800016);
    int*   blocksum = (int*)  (ws + 33200016);
    int*   blockoff = (int*)  (ws + 33202016);

    const int eGrid = (NE + 255) / 256;

    // ---- CSR build (amortized across all 3 layers) ----
    hipMemsetAsync(cnt, 0, NN * sizeof(int), stream);
    hist_dst<<<eGrid, 256, 0, stream>>>(dst, cnt);
    scan_partial<<<SCAN_NB, SCAN_B, 0, stream>>>(cnt, blocksum);
    scan_blocksums<<<1, 512, 0, stream>>>(blocksum, blockoff);
    scan_final<<<SCAN_NB, SCAN_B, 0, stream>>>(cnt, blockoff, rowstart, dinv);
    hipMemsetAsync(cnt, 0, NN * sizeof(int), stream);
    scatter_csr<<<eGrid, 256, 0, stream>>>(src, dst, rowstart, cnt, srcidx);

    const int gemmGrid = (NN + 63) / 64;
    const int aggrGrid = (NN + 3) / 4;      // 4 waves (nodes) per 256-block

    gemm_scale<<<gemmGrid, 256, 0, stream>>>(x, W1, dinv, y, NN);
    pull_aggr<<<aggrGrid, 256, 0, stream>>>(rowstart, srcidx, y, dinv, b1, h1);

    gemm_scale<<<gemmGrid, 256, 0, stream>>>(h1, W2, dinv, y, NN);
    pull_aggr<<<aggrGrid, 256, 0, stream>>>(rowstart, srcidx, y, dinv, b2, h2);

    gemm_scale<<<gemmGrid, 256, 0, stream>>>(h2, W3, dinv, y, NN);
    pull_aggr<<<aggrGrid, 256, 0, stream>>>(rowstart, srcidx, y, dinv, b3, h3);

    pool_ffn<<<NG, 64, 0, stream>>>(h3, bat, Wf, bf, pooled, ffn, soft);
}